// Round 3
// baseline (236.686 us; speedup 1.0000x reference)
//
#include <hip/hip_runtime.h>
#include <stdint.h>

// Wavelet low-pass analysis (stride-2) + synthesis (transposed conv) fused
// into two 18-tap polyphase FIR filters applied directly to the input:
//   even p: ya[p] = sum_d We[d] * sig_m[p - 8 + d]
//   odd  p: ya[p] = sum_d Wo[d] * sig_m[p - 9 + d]
// sig_m = symmetric extension of the 524288-long flattened per-batch signal.
//
// v4: T3 minimum 2-phase pipeline. v3 was latency-bound at 31% HBM: 16384
// one-shot workgroups each paid the full un-overlapped global->LDS latency
// plus launch/teardown (~60 cyc/wg/XCD dispatch rate). Now 2048 persistent
// blocks x 8 tiles with double-buffered LDS: STAGE(tile t+1) is issued
// BEFORE computing tile t, so HBM latency hides under the 144-FMA compute
// phase; one vmcnt(0)+barrier per tile (__syncthreads) drains a prefetch
// that has already had ~700 cycles to land.

#define L_SIG 524288             // flattened per-batch length (128*4096) = 2^19
#define TILE  2048
#define HALO  16                 // only +-9 needed; 16 keeps float4 alignment
#define TPB_F (TILE + 2 * HALO)  // 2080 floats per buffer
#define TILES_PER_BATCH (L_SIG / TILE)         // 256
#define NBLOCKS 2048
#define TILES_PER_BLOCK 8        // 16384 tiles / 2048 blocks

typedef float f4 __attribute__((ext_vector_type(4)));

typedef __attribute__((address_space(3))) uint32_t lds_u32_t;
typedef const __attribute__((address_space(1))) uint32_t glb_u32_t;

// Async global->LDS DMA, 16 B per lane. LDS dest is wave-uniform base +
// lane*16 (m104); our lane-linear layout matches exactly (verified v3).
__device__ __forceinline__ void stage16(const float* g, float* l) {
    __builtin_amdgcn_global_load_lds((glb_u32_t*)g, (lds_u32_t*)l, 16, 0, 0);
}

constexpr float RL[10] = {
    0.160102397974125f,   0.6038292697974729f,  0.7243085284385744f,
    0.13842814590110342f, -0.24229488706619015f, -0.03224486958502952f,
    0.07757149384006515f, -0.006241490213011705f, -0.012580751999015526f,
    0.003335725285001549f};

struct Coef { float we[18]; float wo[18]; };

constexpr Coef make_coef() {
    Coef c{};
    for (int d = 0; d < 18; ++d) {
        float se = 0.f, so = 0.f;
        for (int j = 0; j < 5; ++j) {
            int i = d - 2 * j;               // REC_LO tap index
            if (i >= 0 && i < 10) {
                se += RL[8 - 2 * j] * RL[i]; // DEC_LO[2j+1] = RL[8-2j]
                so += RL[9 - 2 * j] * RL[i]; // DEC_LO[2j]   = RL[9-2j]
            }
        }
        c.we[d] = se;
        c.wo[d] = so;
    }
    return c;
}

constexpr Coef CF = make_coef();

__global__ __launch_bounds__(256)
void wavelet_fused_kernel(const float* __restrict__ x, float* __restrict__ out) {
    __shared__ float s[2][TPB_F];   // 2 x 8320 B double buffer
    const int t    = threadIdx.x;
    const int tau0 = blockIdx.x * TILES_PER_BLOCK;   // first tile of this block

    // Stage tile tau into LDS buffer buf.
    auto stage = [&](int tau, float* buf) {
        const int    tb = tau & (TILES_PER_BATCH - 1);
        const float* xb = x + ((size_t)(tau >> 8) << 19);   // batch base
        const int    p0 = tb * TILE;
        if (tb == 0 || tb == TILES_PER_BATCH - 1) {
            // Symmetric-mirror staging (1 tile in every 32 per block avg).
            for (int i = t; i < TPB_F; i += 256) {
                int k  = p0 - HALO + i;
                int km = (k < 0) ? (-1 - k) : ((k >= L_SIG) ? (2 * L_SIG - 1 - k) : k);
                buf[i] = xb[km];
            }
        } else {
            // Interior: 2080 floats via async DMA, 16B-aligned.
            const float* src = xb + p0 - HALO;
            stage16(src + 4 * t,        buf + 4 * t);
            stage16(src + 1024 + 4 * t, buf + 1024 + 4 * t);
            if (t < 8)
                stage16(src + 2048 + 4 * t, buf + 2048 + 4 * t);
        }
    };

    // Prologue: fill buffer 0 (only un-overlapped load of the block).
    stage(tau0, s[0]);
    __syncthreads();

    int cur = 0;
#pragma unroll 1
    for (int it = 0; it < TILES_PER_BLOCK; ++it) {
        const int tau = tau0 + it;

        // Issue next tile's loads FIRST -- latency hides under the FMAs below.
        if (it + 1 < TILES_PER_BLOCK)
            stage(tau + 1, &s[cur ^ 1][0]);

        const float* sb = &s[cur][0];
        float* ob = out + ((size_t)(tau >> 8) << 19)
                        + (size_t)(tau & (TILES_PER_BATCH - 1)) * TILE;

        // Two output quads per thread, 1024 apart (stores 1KB-coalesced,
        // ds_read windows at 16B lane stride: 0 bank conflicts measured).
#pragma unroll
        for (int h = 0; h < 2; ++h) {
            const int q = 4 * t + 1024 * h;

            float v[20];
            const f4* sp = (const f4*)(sb + q + 8);  // = x[p0 + q - 8 ...]
#pragma unroll
            for (int r = 0; r < 5; ++r) {
                f4 f = sp[r];
                v[4 * r + 0] = f[0];
                v[4 * r + 1] = f[1];
                v[4 * r + 2] = f[2];
                v[4 * r + 3] = f[3];
            }

            float o0 = 0.f, o1 = 0.f, o2 = 0.f, o3 = 0.f;
#pragma unroll
            for (int d = 0; d < 18; ++d) {
                o0 += CF.we[d] * v[d];       // even output at q   : x[q-8+d]
                o1 += CF.wo[d] * v[d];       // odd  output at q+1 : x[(q+1)-9+d]
                o2 += CF.we[d] * v[d + 2];   // even output at q+2
                o3 += CF.wo[d] * v[d + 2];   // odd  output at q+3
            }

            f4 o = {o0, o1, o2, o3};
            __builtin_nontemporal_store(o, (f4*)(ob + q));
        }

        // One drain per tile: waits the prefetch (issued ~700 cyc ago) and
        // fences buf[cur] readers before iteration it+1 overwrites it.
        __syncthreads();
        cur ^= 1;
    }
}

extern "C" void kernel_launch(void* const* d_in, const int* in_sizes, int n_in,
                              void* d_out, int out_size, void* d_ws, size_t ws_size,
                              hipStream_t stream) {
    const float* x = (const float*)d_in[0];
    float* out     = (float*)d_out;
    // 64 batches * 256 tiles/batch = 16384 tiles -> 2048 blocks x 8 tiles.
    wavelet_fused_kernel<<<NBLOCKS, 256, 0, stream>>>(x, out);
}

// Round 4
// 229.003 us; speedup vs baseline: 1.0335x; 1.0335x over previous
//
#include <hip/hip_runtime.h>
#include <stdint.h>

// Wavelet low-pass analysis (stride-2) + synthesis (transposed conv) fused
// into two 18-tap polyphase FIR filters applied directly to the input:
//   even p: ya[p] = sum_d We[d] * sig_m[p - 8 + d]
//   odd  p: ya[p] = sum_d Wo[d] * sig_m[p - 9 + d]
// sig_m = symmetric extension of the 524288-long flattened per-batch signal.
//
// v5: v3 structure, PLAIN stores. A/B vs round-2 (81 us): v2/v3/v4 all used
// __builtin_nontemporal_store and all landed 81-88 us at ~1.6 TB/s write
// throughput; the round-0 baseline with plain stores was ~71 us. Theory: nt
// skips L2 allocation, so each store holds the CU store queue until HBM acks
// (~600-900 cyc) -> per-CU write throughput caps at ~2.7 B/cyc. Plain stores
// ack at L2 (~100 cyc) and drain lazily. Only the store instruction changes.

#define L_SIG 524288            // flattened per-batch length (128*4096) = 2^19
#define TILE  2048
#define HALO  16                // only +-9 needed; 16 keeps float4 alignment
#define SMEM_N (TILE + 2 * HALO) // 2080 floats = 8320 B

typedef float f4 __attribute__((ext_vector_type(4)));

typedef __attribute__((address_space(3))) uint32_t lds_u32_t;
typedef const __attribute__((address_space(1))) uint32_t glb_u32_t;

// Async global->LDS DMA, 16 B per lane. LDS dest is wave-uniform base +
// lane*16 (m104) -- our lane-linear layout matches exactly (verified v3).
__device__ __forceinline__ void stage16(const float* g, float* l) {
    __builtin_amdgcn_global_load_lds((glb_u32_t*)g, (lds_u32_t*)l, 16, 0, 0);
}

constexpr float RL[10] = {
    0.160102397974125f,   0.6038292697974729f,  0.7243085284385744f,
    0.13842814590110342f, -0.24229488706619015f, -0.03224486958502952f,
    0.07757149384006515f, -0.006241490213011705f, -0.012580751999015526f,
    0.003335725285001549f};

struct Coef { float we[18]; float wo[18]; };

constexpr Coef make_coef() {
    Coef c{};
    for (int d = 0; d < 18; ++d) {
        float se = 0.f, so = 0.f;
        for (int j = 0; j < 5; ++j) {
            int i = d - 2 * j;               // REC_LO tap index
            if (i >= 0 && i < 10) {
                se += RL[8 - 2 * j] * RL[i]; // DEC_LO[2j+1] = RL[8-2j]
                so += RL[9 - 2 * j] * RL[i]; // DEC_LO[2j]   = RL[9-2j]
            }
        }
        c.we[d] = se;
        c.wo[d] = so;
    }
    return c;
}

constexpr Coef CF = make_coef();

__global__ __launch_bounds__(256)
void wavelet_fused_kernel(const float* __restrict__ x, float* __restrict__ out) {
    __shared__ float s[SMEM_N];

    const int batch = blockIdx.y;
    const int p0    = blockIdx.x * TILE;
    const float* xb = x   + (size_t)batch * L_SIG;
    float*       ob = out + (size_t)batch * L_SIG;
    const int t = threadIdx.x;

    const bool edge = (blockIdx.x == 0) || (blockIdx.x == gridDim.x - 1);

    if (edge) {
        // Scalar mirror staging (2 blocks/batch = 128 of 16384 blocks).
        // global_load_lds can't express the element-reversed mirror.
        for (int i = t; i < SMEM_N; i += 256) {
            int k  = p0 - HALO + i;
            int km = (k < 0) ? (-1 - k) : ((k >= L_SIG) ? (2 * L_SIG - 1 - k) : k);
            s[i] = xb[km];
        }
    } else {
        // Interior: 2080 floats staged by 2 full-width DMA calls + 8-lane tail.
        const float* src = xb + p0 - HALO;   // 16B-aligned (p0 % 2048 == 0)
        stage16(src + 4 * t,        s + 4 * t);
        stage16(src + 1024 + 4 * t, s + 1024 + 4 * t);
        if (t < 8)
            stage16(src + 2048 + 4 * t, s + 2048 + 4 * t);
    }
    __syncthreads();   // barrier drain waits vmcnt(0): DMA complete

    // Two output quads per thread, 1024 apart (stores stay 1KB-coalesced,
    // ds_read windows keep the 16B lane stride: 0 bank conflicts measured).
#pragma unroll
    for (int h = 0; h < 2; ++h) {
        const int q = 4 * t + 1024 * h;      // local output index

        float v[20];
        const f4* sp = (const f4*)(s + q + 8);  // = x[p0 + q - 8 ...]
#pragma unroll
        for (int r = 0; r < 5; ++r) {
            f4 f = sp[r];
            v[4 * r + 0] = f[0];
            v[4 * r + 1] = f[1];
            v[4 * r + 2] = f[2];
            v[4 * r + 3] = f[3];
        }

        float o0 = 0.f, o1 = 0.f, o2 = 0.f, o3 = 0.f;
#pragma unroll
        for (int d = 0; d < 18; ++d) {
            o0 += CF.we[d] * v[d];       // even output at q   : x[q-8+d]
            o1 += CF.wo[d] * v[d];       // odd  output at q+1 : x[(q+1)-9+d]
            o2 += CF.we[d] * v[d + 2];   // even output at q+2
            o3 += CF.wo[d] * v[d + 2];   // odd  output at q+3
        }

        // PLAIN store: allocates in L2, acks fast, L2 drains to HBM lazily.
        *((f4*)(ob + p0 + q)) = {o0, o1, o2, o3};
    }
}

extern "C" void kernel_launch(void* const* d_in, const int* in_sizes, int n_in,
                              void* d_out, int out_size, void* d_ws, size_t ws_size,
                              hipStream_t stream) {
    const float* x = (const float*)d_in[0];
    float* out     = (float*)d_out;

    const int B = in_sizes[0] / L_SIG;            // 64
    dim3 grid(L_SIG / TILE, B);                   // (256, 64)
    wavelet_fused_kernel<<<grid, 256, 0, stream>>>(x, out);
}

// Round 5
// 221.143 us; speedup vs baseline: 1.0703x; 1.0355x over previous
//
#include <hip/hip_runtime.h>
#include <stdint.h>

// Wavelet low-pass analysis (stride-2) + synthesis (transposed conv) fused
// into two 18-tap polyphase FIR filters applied directly to the input:
//   even p: ya[p] = sum_d We[d] * sig_m[p - 8 + d]
//   odd  p: ya[p] = sum_d Wo[d] * sig_m[p - 9 + d]
// sig_m = symmetric extension of the 524288-long flattened per-batch signal.
//
// v6: the round-0 champion structure (TILE 1024, 256 threads, 1 output
// quad/thread, plain stores, one-shot blocks -- 220.4 us total / ~71 us
// kernel) with EXACTLY ONE change: interior staging via
// __builtin_amdgcn_global_load_lds width=16 instead of float4->VGPR->
// ds_write. Completes the {tile}x{staging} bisect: (1024,VGPR)=71,
// (2048,DMA)=80-81. If this lands ~71 the tile size was v3's regression;
// if ~81 the DMA staging is, and we revert it next round.

#define L_SIG 524288            // flattened per-batch length (128*4096) = 2^19
#define TILE  1024
#define HALO  16                // only +-9 needed; 16 keeps float4 alignment
#define SMEM_N (TILE + 2 * HALO) // 1056 floats = 4224 B

typedef float f4 __attribute__((ext_vector_type(4)));

typedef __attribute__((address_space(3))) uint32_t lds_u32_t;
typedef const __attribute__((address_space(1))) uint32_t glb_u32_t;

// Async global->LDS DMA, 16 B per lane. LDS dest is wave-uniform base +
// lane*16 (m104) -- lane-linear layout matches exactly (verified r2/r4).
__device__ __forceinline__ void stage16(const float* g, float* l) {
    __builtin_amdgcn_global_load_lds((glb_u32_t*)g, (lds_u32_t*)l, 16, 0, 0);
}

constexpr float RL[10] = {
    0.160102397974125f,   0.6038292697974729f,  0.7243085284385744f,
    0.13842814590110342f, -0.24229488706619015f, -0.03224486958502952f,
    0.07757149384006515f, -0.006241490213011705f, -0.012580751999015526f,
    0.003335725285001549f};

struct Coef { float we[18]; float wo[18]; };

constexpr Coef make_coef() {
    Coef c{};
    for (int d = 0; d < 18; ++d) {
        float se = 0.f, so = 0.f;
        for (int j = 0; j < 5; ++j) {
            int i = d - 2 * j;               // REC_LO tap index
            if (i >= 0 && i < 10) {
                se += RL[8 - 2 * j] * RL[i]; // DEC_LO[2j+1] = RL[8-2j]
                so += RL[9 - 2 * j] * RL[i]; // DEC_LO[2j]   = RL[9-2j]
            }
        }
        c.we[d] = se;
        c.wo[d] = so;
    }
    return c;
}

constexpr Coef CF = make_coef();

__global__ __launch_bounds__(256)
void wavelet_fused_kernel(const float* __restrict__ x, float* __restrict__ out) {
    __shared__ float s[SMEM_N];

    const int batch = blockIdx.y;
    const int p0    = blockIdx.x * TILE;
    const float* xb = x   + (size_t)batch * L_SIG;
    float*       ob = out + (size_t)batch * L_SIG;
    const int t = threadIdx.x;

    const bool edge = (blockIdx.x == 0) || (blockIdx.x == gridDim.x - 1);

    if (edge) {
        // Scalar mirror staging (2 blocks/batch = 128 of 32768 blocks).
        // global_load_lds can't express the element-reversed mirror.
        for (int i = t; i < SMEM_N; i += 256) {
            int k  = p0 - HALO + i;
            int km = (k < 0) ? (-1 - k) : ((k >= L_SIG) ? (2 * L_SIG - 1 - k) : k);
            s[i] = xb[km];
        }
    } else {
        // Interior: 1056 floats = 264 float4 via async DMA, 16B-aligned
        // (p0 - 16 is float4-aligned since p0 % 1024 == 0).
        const float* src = xb + p0 - HALO;
        stage16(src + 4 * t, s + 4 * t);
        if (t < 8)
            stage16(src + 1024 + 4 * t, s + 1024 + 4 * t);
    }
    __syncthreads();   // barrier drain waits vmcnt(0): DMA complete

    // One output quad per thread: outputs p0+q .. p0+q+3 (even,odd,even,odd).
    const int q = 4 * t;

    float v[20];
    const f4* sp = (const f4*)(s + q + 8);  // = x[p0 + q - 8 ...]
#pragma unroll
    for (int r = 0; r < 5; ++r) {
        f4 f = sp[r];
        v[4 * r + 0] = f[0];
        v[4 * r + 1] = f[1];
        v[4 * r + 2] = f[2];
        v[4 * r + 3] = f[3];
    }

    float o0 = 0.f, o1 = 0.f, o2 = 0.f, o3 = 0.f;
#pragma unroll
    for (int d = 0; d < 18; ++d) {
        o0 += CF.we[d] * v[d];       // even output at q   : x[q-8+d]
        o1 += CF.wo[d] * v[d];       // odd  output at q+1 : x[(q+1)-9+d]
        o2 += CF.we[d] * v[d + 2];   // even output at q+2
        o3 += CF.wo[d] * v[d + 2];   // odd  output at q+3
    }

    // Plain store: acks at L2, drains to HBM lazily (no barrier follows).
    *((f4*)(ob + p0 + q)) = {o0, o1, o2, o3};
}

extern "C" void kernel_launch(void* const* d_in, const int* in_sizes, int n_in,
                              void* d_out, int out_size, void* d_ws, size_t ws_size,
                              hipStream_t stream) {
    const float* x = (const float*)d_in[0];
    float* out     = (float*)d_out;

    const int B = in_sizes[0] / L_SIG;            // 64
    dim3 grid(L_SIG / TILE, B);                   // (512, 64)
    wavelet_fused_kernel<<<grid, 256, 0, stream>>>(x, out);
}